// Round 8
// baseline (137.730 us; speedup 1.0000x reference)
//
#include <hip/hip_runtime.h>
#include <hip/hip_bf16.h>

// TTT-MLP, round 8: best-of-measured split pipeline.
//   out = LN( h @ Weq^T + beq ),  h = relu(x@W1^T + b1)
//   Weq = Wo@W2, beq = Wo@b2 + bo   (TTT inner loop never updates weights)
// G1 = round-2's fused x-cast GEMM (fp32 A staged direct via global_load_lds,
//      cast at fragment read, 48KB LDS -> 3 blocks/CU, measured ~32us).
// G2 = round-4's 2-phase dbuf 128^2 (2 blocks/CU, measured ~36us).
// LN = wave-per-row bf16->fp32 (measured ~22us = HBM roofline).

#define HIDDEN 768
#define INNER  512

typedef __bf16 bf16_t;
typedef bf16_t bf16x8 __attribute__((ext_vector_type(8)));
typedef bf16_t bf16x4 __attribute__((ext_vector_type(4)));
typedef float  f32x4  __attribute__((ext_vector_type(4)));

__device__ __forceinline__ void async16(const void* g, void* lds) {
  __builtin_amdgcn_global_load_lds(
      (const __attribute__((address_space(1))) unsigned int*)g,
      (__attribute__((address_space(3))) unsigned int*)lds, 16, 0, 0);
}

// ---------------------------------------------------------------- prep: weight casts + W2 transpose
// blocks [0,24): W1 cast ; [24,60): Wo cast ; [60,156): W2 -> W2t (bf16, transposed)
__global__ __launch_bounds__(256)
void prep(const float* __restrict__ W1, const float* __restrict__ W2,
          const float* __restrict__ Wo, bf16_t* __restrict__ W1b,
          bf16_t* __restrict__ W2t, bf16_t* __restrict__ Wob) {
  __shared__ float T[64][65];
  const int b = blockIdx.x, t = threadIdx.x;

  const float4* src; bf16x4* dst; int base;
  if (b < 24)       { src = (const float4*)W1; dst = (bf16x4*)W1b; base = b * 4096; }
  else if (b < 60)  { src = (const float4*)Wo; dst = (bf16x4*)Wob; base = (b - 24) * 4096; }
  else {
    const int tile = b - 60;
    const int d0 = (tile >> 3) << 6;
    const int i0 = (tile & 7) << 6;
#pragma unroll
    for (int j = 0; j < 4; ++j) {
      const int idx = j * 256 + t;
      const int r = idx >> 4, c4 = idx & 15;
      float4 v = *(const float4*)(W2 + (size_t)(d0 + r) * INNER + i0 + c4 * 4);
      T[r][c4 * 4 + 0] = v.x; T[r][c4 * 4 + 1] = v.y;
      T[r][c4 * 4 + 2] = v.z; T[r][c4 * 4 + 3] = v.w;
    }
    __syncthreads();
    const int i = t & 63, h4 = t >> 6;
    bf16x8 o0, o1;
#pragma unroll
    for (int c = 0; c < 8; ++c) { o0[c] = (bf16_t)T[h4 * 16 + c][i]; o1[c] = (bf16_t)T[h4 * 16 + 8 + c][i]; }
    bf16_t* orow = W2t + (size_t)(i0 + i) * HIDDEN + d0 + h4 * 16;
    *(bf16x8*)orow = o0;
    *(bf16x8*)(orow + 8) = o1;
    return;
  }
#pragma unroll
  for (int i = 0; i < 16; ++i) {
    float4 v = src[base + i * 256 + t];
    bf16x4 o;
    o[0] = (bf16_t)v.x; o[1] = (bf16_t)v.y; o[2] = (bf16_t)v.z; o[3] = (bf16_t)v.w;
    dst[base + i * 256 + t] = o;
  }
}

// ---------------------------------------------------------------- beq = Wo @ b2 + bo
__global__ __launch_bounds__(256)
void beq_k(const float* __restrict__ Wo, const float* __restrict__ b2,
           const float* __restrict__ bo, float* __restrict__ beq) {
  const int e = blockIdx.x * 4 + (threadIdx.x >> 6);
  const int l = threadIdx.x & 63;
  float s = 0.f;
#pragma unroll
  for (int j = 0; j < 12; ++j) s += Wo[(size_t)e * HIDDEN + j * 64 + l] * b2[j * 64 + l];
#pragma unroll
  for (int off = 1; off < 64; off <<= 1) s += __shfl_xor(s, off, 64);
  if (l == 0) beq[e] = s + bo[e];
}

// ---------------------------------------------------------------- Weq = Wo @ W2 (2-phase 128^2)
__global__ __launch_bounds__(256, 2)
void gemm_weq(const bf16_t* __restrict__ A, const bf16_t* __restrict__ Bt,
              bf16_t* __restrict__ Cout) {
  constexpr int N_ = INNER, K_ = HIDDEN, NT = N_ / 128, T = K_ / 64;
  __shared__ __align__(16) bf16_t As[2][128 * 64];
  __shared__ __align__(16) bf16_t Bs[2][128 * 64];

  const int nb = blockIdx.x;
  const int m0 = (nb / NT) * 128;
  const int n0 = (nb % NT) * 128;

  const int tid = threadIdx.x;
  const int w = tid >> 6, l = tid & 63;
  const int wr = w >> 1, wc = w & 1;
  const int fr = l & 15, fq = l >> 4;

#define STAGEW(dst, src, r0, k0)                                              \
  _Pragma("unroll") for (int i = 0; i < 4; ++i) {                             \
    const int G = i * 256 + tid, row = G >> 3, g = G & 7;                     \
    async16((src) + (size_t)((r0) + row) * K_ + (k0) + ((g ^ (row & 7)) << 3),\
            (char*)(dst) + (size_t)(i * 256 + w * 64) * 16);                  \
  }

  STAGEW(As[0], A, m0, 0); STAGEW(Bs[0], Bt, n0, 0);
  __syncthreads();

  f32x4 acc[4][4] = {};
#pragma unroll
  for (int t = 0; t < T; ++t) {
    const int cur = t & 1;
    if (t < T - 1) {
      STAGEW(As[cur ^ 1], A, m0, (t + 1) * 64);
      STAGEW(Bs[cur ^ 1], Bt, n0, (t + 1) * 64);
    }
#pragma unroll
    for (int kk = 0; kk < 2; ++kk) {
      bf16x8 ax[4], bx[4];
#pragma unroll
      for (int m = 0; m < 4; ++m) {
        const int row = wr * 64 + m * 16 + fr;
        const int slot = (kk * 4 + fq) ^ (row & 7);
        ax[m] = *(const bf16x8*)((const char*)As[cur] + row * 128 + slot * 16);
      }
#pragma unroll
      for (int n = 0; n < 4; ++n) {
        const int row = wc * 64 + n * 16 + fr;
        const int slot = (kk * 4 + fq) ^ (row & 7);
        bx[n] = *(const bf16x8*)((const char*)Bs[cur] + row * 128 + slot * 16);
      }
#pragma unroll
      for (int m = 0; m < 4; ++m)
#pragma unroll
        for (int n = 0; n < 4; ++n)
          acc[m][n] = __builtin_amdgcn_mfma_f32_16x16x32_bf16(ax[m], bx[n], acc[m][n], 0, 0, 0);
    }
    __syncthreads();
  }
#undef STAGEW

  const int orow0 = m0 + wr * 64 + fq * 4;
  const int ocol0 = n0 + wc * 64 + fr;
#pragma unroll
  for (int n = 0; n < 4; ++n)
#pragma unroll
    for (int m = 0; m < 4; ++m)
#pragma unroll
      for (int j = 0; j < 4; ++j)
        Cout[(size_t)(orow0 + m * 16 + j) * N_ + ocol0 + n * 16] = (bf16_t)acc[m][n][j];
}

// ---------------------------------------------------------------- G1: h = relu(x @ W1^T + b1)
// Round-2 structure: A = x fp32 staged direct into LDS (async16, swizzled),
// cast at fragment read. 48 KB LDS single-buffered -> 3 blocks/CU.
__global__ __launch_bounds__(256)
void gemm1_xcast(const float* __restrict__ x, const bf16_t* __restrict__ W1b,
                 const float* __restrict__ b1, bf16_t* __restrict__ h) {
  __shared__ __align__(16) float  Asf[128 * 64];   // 32 KB fp32
  __shared__ __align__(16) bf16_t Bs[128 * 64];    // 16 KB bf16

  const int per = gridDim.x >> 3;                  // XCD swizzle (grid%8==0)
  const int nb  = (blockIdx.x & 7) * per + (blockIdx.x >> 3);
  const int m0  = (nb >> 2) * 128;                 // N=512 -> 4 col-tiles
  const int n0  = (nb & 3) * 128;

  const int tid = threadIdx.x;
  const int w = tid >> 6, l = tid & 63;
  const int wr = w >> 1, wc = w & 1;
  const int fr = l & 15, fq = l >> 4;

  f32x4 acc[4][4] = {};

  for (int k0 = 0; k0 < HIDDEN; k0 += 64) {
    __syncthreads();
    // A: 128x64 fp32 = 2048 granules(16B), 8 issues/thread, source-swizzled
#pragma unroll
    for (int i = 0; i < 8; ++i) {
      const int G = i * 256 + tid;
      const int row = G >> 4, g = G & 15;
      const int gs = (g & 8) | ((g ^ row) & 7);
      async16(x + (size_t)(m0 + row) * HIDDEN + k0 + gs * 4,
              (char*)Asf + (size_t)(i * 256 + w * 64) * 16);
    }
    // B: 128x64 bf16 = 1024 granules, 4 issues/thread, source-swizzled
#pragma unroll
    for (int i = 0; i < 4; ++i) {
      const int G = i * 256 + tid;
      const int row = G >> 3, g = G & 7;
      async16(W1b + (size_t)(n0 + row) * HIDDEN + k0 + ((g ^ (row & 7)) << 3),
              (char*)Bs + (size_t)(i * 256 + w * 64) * 16);
    }
    __syncthreads();

#pragma unroll
    for (int kk = 0; kk < 2; ++kk) {
      bf16x8 ax[4], bx[4];
#pragma unroll
      for (int m = 0; m < 4; ++m) {
        const int row = wr * 64 + m * 16 + fr;
        const int g0 = kk * 8 + fq * 2;
        const int s0 = (g0 & 8) | ((g0 ^ row) & 7);
        const int s1 = ((g0 + 1) & 8) | (((g0 + 1) ^ row) & 7);
        f32x4 p0 = *(const f32x4*)(Asf + row * 64 + s0 * 4);
        f32x4 p1 = *(const f32x4*)(Asf + row * 64 + s1 * 4);
        bf16x8 a;
#pragma unroll
        for (int c = 0; c < 4; ++c) { a[c] = (bf16_t)p0[c]; a[4 + c] = (bf16_t)p1[c]; }
        ax[m] = a;
      }
#pragma unroll
      for (int n = 0; n < 4; ++n) {
        const int row = wc * 64 + n * 16 + fr;
        const int slot = (kk * 4 + fq) ^ (row & 7);
        bx[n] = *(const bf16x8*)((const char*)Bs + row * 128 + slot * 16);
      }
#pragma unroll
      for (int m = 0; m < 4; ++m)
#pragma unroll
        for (int n = 0; n < 4; ++n)
          acc[m][n] = __builtin_amdgcn_mfma_f32_16x16x32_bf16(ax[m], bx[n], acc[m][n], 0, 0, 0);
    }
  }

  const int orow0 = m0 + wr * 64 + fq * 4;
  const int ocol0 = n0 + wc * 64 + fr;
#pragma unroll
  for (int n = 0; n < 4; ++n) {
    const int col = ocol0 + n * 16;
    const float bv = b1[col];
#pragma unroll
    for (int m = 0; m < 4; ++m)
#pragma unroll
      for (int j = 0; j < 4; ++j)
        h[(size_t)(orow0 + m * 16 + j) * INNER + col] = (bf16_t)fmaxf(acc[m][n][j] + bv, 0.f);
  }
}

// ---------------------------------------------------------------- G2: raw = h @ Weq^T + beq (2-phase)
__global__ __launch_bounds__(256, 2)
void gemm2(const bf16_t* __restrict__ A, const bf16_t* __restrict__ Bt,
           const float* __restrict__ bias, bf16_t* __restrict__ Cout) {
  constexpr int N_ = HIDDEN, K_ = INNER, NT = N_ / 128, T = K_ / 64;
  __shared__ __align__(16) bf16_t As[2][128 * 64];
  __shared__ __align__(16) bf16_t Bs[2][128 * 64];

  const int per = gridDim.x >> 3;
  const int nb  = (blockIdx.x & 7) * per + (blockIdx.x >> 3);
  const int m0 = (nb / NT) * 128;
  const int n0 = (nb % NT) * 128;

  const int tid = threadIdx.x;
  const int w = tid >> 6, l = tid & 63;
  const int wr = w >> 1, wc = w & 1;
  const int fr = l & 15, fq = l >> 4;

#define STAGE(dst, src, r0, k0)                                               \
  _Pragma("unroll") for (int i = 0; i < 4; ++i) {                             \
    const int G = i * 256 + tid, row = G >> 3, g = G & 7;                     \
    async16((src) + (size_t)((r0) + row) * K_ + (k0) + ((g ^ (row & 7)) << 3),\
            (char*)(dst) + (size_t)(i * 256 + w * 64) * 16);                  \
  }

  STAGE(As[0], A, m0, 0); STAGE(Bs[0], Bt, n0, 0);
  __syncthreads();

  f32x4 acc[4][4] = {};
#pragma unroll
  for (int t = 0; t < T; ++t) {
    const int cur = t & 1;
    if (t < T - 1) {
      STAGE(As[cur ^ 1], A, m0, (t + 1) * 64);
      STAGE(Bs[cur ^ 1], Bt, n0, (t + 1) * 64);
    }
#pragma unroll
    for (int kk = 0; kk < 2; ++kk) {
      bf16x8 ax[4], bx[4];
#pragma unroll
      for (int m = 0; m < 4; ++m) {
        const int row = wr * 64 + m * 16 + fr;
        const int slot = (kk * 4 + fq) ^ (row & 7);
        ax[m] = *(const bf16x8*)((const char*)As[cur] + row * 128 + slot * 16);
      }
#pragma unroll
      for (int n = 0; n < 4; ++n) {
        const int row = wc * 64 + n * 16 + fr;
        const int slot = (kk * 4 + fq) ^ (row & 7);
        bx[n] = *(const bf16x8*)((const char*)Bs[cur] + row * 128 + slot * 16);
      }
#pragma unroll
      for (int m = 0; m < 4; ++m)
#pragma unroll
        for (int n = 0; n < 4; ++n)
          acc[m][n] = __builtin_amdgcn_mfma_f32_16x16x32_bf16(ax[m], bx[n], acc[m][n], 0, 0, 0);
    }
    __syncthreads();
  }
#undef STAGE

  const int orow0 = m0 + wr * 64 + fq * 4;
  const int ocol0 = n0 + wc * 64 + fr;
#pragma unroll
  for (int n = 0; n < 4; ++n) {
    const int col = ocol0 + n * 16;
    const float bv = bias[col];
#pragma unroll
    for (int m = 0; m < 4; ++m)
#pragma unroll
      for (int j = 0; j < 4; ++j)
        Cout[(size_t)(orow0 + m * 16 + j) * N_ + col] = (bf16_t)(acc[m][n][j] + bv);
  }
}

// ---------------------------------------------------------------- LN: bf16 raw -> fp32 out
__global__ __launch_bounds__(256)
void ln_bf16(const bf16_t* __restrict__ raw, const float* __restrict__ gamma,
             const float* __restrict__ beta, float* __restrict__ out) {
  const int r = blockIdx.x * 4 + (threadIdx.x >> 6);
  const int l = threadIdx.x & 63;
  const bf16_t* rp = raw + (size_t)r * HIDDEN;
  float v[12];
  float s = 0.f, q = 0.f;
#pragma unroll
  for (int c = 0; c < 3; ++c) {
    bf16x4 b4 = *(const bf16x4*)(rp + c * 256 + l * 4);
#pragma unroll
    for (int j = 0; j < 4; ++j) {
      const float f = (float)b4[j];
      v[c * 4 + j] = f; s += f; q += f * f;
    }
  }
#pragma unroll
  for (int off = 1; off < 64; off <<= 1) {
    s += __shfl_xor(s, off, 64);
    q += __shfl_xor(q, off, 64);
  }
  const float mu  = s * (1.0f / HIDDEN);
  const float var = fmaxf(q * (1.0f / HIDDEN) - mu * mu, 0.f);
  const float inv = rsqrtf(var + 1e-5f);
  float* op = out + (size_t)r * HIDDEN;
#pragma unroll
  for (int c = 0; c < 3; ++c) {
    float4 g = ((const float4*)gamma)[c * 64 + l];
    float4 b = ((const float4*)beta)[c * 64 + l];
    float4 o;
    o.x = (v[c * 4 + 0] - mu) * inv * g.x + b.x;
    o.y = (v[c * 4 + 1] - mu) * inv * g.y + b.y;
    o.z = (v[c * 4 + 2] - mu) * inv * g.z + b.z;
    o.w = (v[c * 4 + 3] - mu) * inv * g.w + b.w;
    ((float4*)op)[c * 64 + l] = o;
  }
}

// ---------------------------------------------------------------- launch
extern "C" void kernel_launch(void* const* d_in, const int* in_sizes, int n_in,
                              void* d_out, int out_size, void* d_ws, size_t ws_size,
                              hipStream_t stream) {
  const float* x     = (const float*)d_in[0];
  const float* W1    = (const float*)d_in[1];
  const float* b1    = (const float*)d_in[2];
  const float* W2    = (const float*)d_in[3];
  const float* b2    = (const float*)d_in[4];
  const float* Wo    = (const float*)d_in[5];
  const float* bo    = (const float*)d_in[6];
  const float* gamma = (const float*)d_in[7];
  const float* beta  = (const float*)d_in[8];

  const int M = in_sizes[0] / HIDDEN;   // 32768 tokens

  // ws: raw (bf16 M*768) | h (bf16 M*512) | W1b | W2t | Wob | Weq | beq
  char* ws = (char*)d_ws;
  bf16_t* raw  = (bf16_t*)ws;
  bf16_t* h    = (bf16_t*)(ws + (size_t)M * HIDDEN * 2);
  bf16_t* W1b  = (bf16_t*)(ws + (size_t)M * HIDDEN * 2 + (size_t)M * INNER * 2);
  bf16_t* W2t  = W1b + INNER * HIDDEN;                   // [512,768]
  bf16_t* Wob  = W2t + INNER * HIDDEN;                   // [768,768]
  bf16_t* Weq  = Wob + HIDDEN * HIDDEN;                  // [768,512]
  float*  beq  = (float*)(Weq + HIDDEN * INNER);

  prep<<<156, 256, 0, stream>>>(W1, W2, Wo, W1b, W2t, Wob);
  beq_k<<<HIDDEN / 4, 256, 0, stream>>>(Wo, b2, bo, beq);

  // Weq = Wo @ W2 : A=Wob [768,768], Bt=W2t [512,768] -> [768,512]
  gemm_weq<<<(HIDDEN / 128) * (INNER / 128), 256, 0, stream>>>(Wob, W2t, Weq);
  // h = relu(x @ W1^T + b1)   (fp32 x staged directly, cast at frag read)
  gemm1_xcast<<<(M / 128) * (INNER / 128), 256, 0, stream>>>(x, W1b, b1, h);
  // raw = h @ Weq^T + beq   (bf16)
  gemm2<<<(M / 128) * (HIDDEN / 128), 256, 0, stream>>>(h, Weq, beq, raw);
  // out = LN(raw)
  ln_bf16<<<M / 4, 256, 0, stream>>>(raw, gamma, beta, (float*)d_out);
}

// Round 9
// 132.967 us; speedup vs baseline: 1.0358x; 1.0358x over previous
//
#include <hip/hip_runtime.h>
#include <hip/hip_bf16.h>

// TTT-MLP, round 9.  out = LN( h @ Weq^T + beq ),  h = relu(x@W1^T + b1),
// Weq = Wo@W2, beq = Wo@b2 + bo  (TTT inner loop never updates weights).
// R4 split pipeline (measured-best components) + T4 counted-vmcnt GEMM loop:
// STAGE(next); s_waitcnt vmcnt(8); s_barrier; compute(cur); s_barrier
// -- next-tile loads stay in flight across barriers (never drained to 0).

#define HIDDEN 768
#define INNER  512

typedef __bf16 bf16_t;
typedef bf16_t bf16x8 __attribute__((ext_vector_type(8)));
typedef bf16_t bf16x4 __attribute__((ext_vector_type(4)));
typedef float  f32x4  __attribute__((ext_vector_type(4)));

__device__ __forceinline__ void async16(const void* g, void* lds) {
  __builtin_amdgcn_global_load_lds(
      (const __attribute__((address_space(1))) unsigned int*)g,
      (__attribute__((address_space(3))) unsigned int*)lds, 16, 0, 0);
}

// ---------------------------------------------------------------- prep
// [0,xb): x->bf16 ; [+24): W1 ; [+36): Wo ; [+96): W2->W2t ; [+192): beq rows
__global__ __launch_bounds__(256)
void prep(const float* __restrict__ x, const float* __restrict__ W1,
          const float* __restrict__ W2, const float* __restrict__ Wo,
          const float* __restrict__ b2, const float* __restrict__ bo,
          bf16_t* __restrict__ xb, bf16_t* __restrict__ W1b,
          bf16_t* __restrict__ W2t, bf16_t* __restrict__ Wob,
          float* __restrict__ beq, int xb_blocks) {
  __shared__ float T[64][65];
  const int b = blockIdx.x, t = threadIdx.x;

  const float4* src; bf16x4* dst; int base;
  if (b < xb_blocks)           { src = (const float4*)x;  dst = (bf16x4*)xb;  base = b * 4096; }
  else if (b < xb_blocks + 24) { src = (const float4*)W1; dst = (bf16x4*)W1b; base = (b - xb_blocks) * 4096; }
  else if (b < xb_blocks + 60) { src = (const float4*)Wo; dst = (bf16x4*)Wob; base = (b - xb_blocks - 24) * 4096; }
  else if (b < xb_blocks + 156) {
    // W2 [768,512] -> W2t [512,768], 64x64 tile per block (96 tiles)
    const int tile = b - xb_blocks - 60;
    const int d0 = (tile >> 3) << 6;
    const int i0 = (tile & 7) << 6;
#pragma unroll
    for (int j = 0; j < 4; ++j) {
      const int idx = j * 256 + t;
      const int r = idx >> 4, c4 = idx & 15;
      float4 v = *(const float4*)(W2 + (size_t)(d0 + r) * INNER + i0 + c4 * 4);
      T[r][c4 * 4 + 0] = v.x; T[r][c4 * 4 + 1] = v.y;
      T[r][c4 * 4 + 2] = v.z; T[r][c4 * 4 + 3] = v.w;
    }
    __syncthreads();
    const int i = t & 63, h4 = t >> 6;
    bf16x8 o0, o1;
#pragma unroll
    for (int c = 0; c < 8; ++c) { o0[c] = (bf16_t)T[h4 * 16 + c][i]; o1[c] = (bf16_t)T[h4 * 16 + 8 + c][i]; }
    bf16_t* orow = W2t + (size_t)(i0 + i) * HIDDEN + d0 + h4 * 16;
    *(bf16x8*)orow = o0;
    *(bf16x8*)(orow + 8) = o1;
    return;
  } else {
    // beq = Wo @ b2 + bo : 4 rows per block, wave per row
    const int e = (b - xb_blocks - 156) * 4 + (t >> 6);
    const int l = t & 63;
    float s = 0.f;
#pragma unroll
    for (int j = 0; j < 12; ++j) s += Wo[(size_t)e * HIDDEN + j * 64 + l] * b2[j * 64 + l];
#pragma unroll
    for (int off = 1; off < 64; off <<= 1) s += __shfl_xor(s, off, 64);
    if (l == 0) beq[e] = s + bo[e];
    return;
  }
#pragma unroll
  for (int i = 0; i < 16; ++i) {
    float4 v = src[base + i * 256 + t];
    bf16x4 o;
    o[0] = (bf16_t)v.x; o[1] = (bf16_t)v.y; o[2] = (bf16_t)v.z; o[3] = (bf16_t)v.w;
    dst[base + i * 256 + t] = o;
  }
}

// ---------------------------------------------------------------- Weq = Wo @ W2 (2-phase, tiny)
__global__ __launch_bounds__(256, 2)
void gemm_weq(const bf16_t* __restrict__ A, const bf16_t* __restrict__ Bt,
              bf16_t* __restrict__ Cout) {
  constexpr int N_ = INNER, K_ = HIDDEN, NT = N_ / 128, T = K_ / 64;
  __shared__ __align__(16) bf16_t As[2][128 * 64];
  __shared__ __align__(16) bf16_t Bs[2][128 * 64];

  const int nb = blockIdx.x;
  const int m0 = (nb / NT) * 128;
  const int n0 = (nb % NT) * 128;

  const int tid = threadIdx.x;
  const int w = tid >> 6, l = tid & 63;
  const int wr = w >> 1, wc = w & 1;
  const int fr = l & 15, fq = l >> 4;

#define STAGEW(dst, src, r0, k0)                                              \
  _Pragma("unroll") for (int i = 0; i < 4; ++i) {                             \
    const int G = i * 256 + tid, row = G >> 3, g = G & 7;                     \
    async16((src) + (size_t)((r0) + row) * K_ + (k0) + ((g ^ (row & 7)) << 3),\
            (char*)(dst) + (size_t)(i * 256 + w * 64) * 16);                  \
  }

  STAGEW(As[0], A, m0, 0); STAGEW(Bs[0], Bt, n0, 0);
  __syncthreads();

  f32x4 acc[4][4] = {};
#pragma unroll
  for (int t = 0; t < T; ++t) {
    const int cur = t & 1;
    if (t < T - 1) {
      STAGEW(As[cur ^ 1], A, m0, (t + 1) * 64);
      STAGEW(Bs[cur ^ 1], Bt, n0, (t + 1) * 64);
    }
#pragma unroll
    for (int kk = 0; kk < 2; ++kk) {
      bf16x8 ax[4], bx[4];
#pragma unroll
      for (int m = 0; m < 4; ++m) {
        const int row = wr * 64 + m * 16 + fr;
        const int slot = (kk * 4 + fq) ^ (row & 7);
        ax[m] = *(const bf16x8*)((const char*)As[cur] + row * 128 + slot * 16);
      }
#pragma unroll
      for (int n = 0; n < 4; ++n) {
        const int row = wc * 64 + n * 16 + fr;
        const int slot = (kk * 4 + fq) ^ (row & 7);
        bx[n] = *(const bf16x8*)((const char*)Bs[cur] + row * 128 + slot * 16);
      }
#pragma unroll
      for (int m = 0; m < 4; ++m)
#pragma unroll
        for (int n = 0; n < 4; ++n)
          acc[m][n] = __builtin_amdgcn_mfma_f32_16x16x32_bf16(ax[m], bx[n], acc[m][n], 0, 0, 0);
    }
    __syncthreads();
  }
#undef STAGEW

  const int orow0 = m0 + wr * 64 + fq * 4;
  const int ocol0 = n0 + wc * 64 + fr;
#pragma unroll
  for (int n = 0; n < 4; ++n)
#pragma unroll
    for (int m = 0; m < 4; ++m)
#pragma unroll
      for (int j = 0; j < 4; ++j)
        Cout[(size_t)(orow0 + m * 16 + j) * N_ + ocol0 + n * 16] = (bf16_t)acc[m][n][j];
}

// ---------------------------------------------------------------- main GEMM, counted-vmcnt 2-phase
// MODE 0: bias+relu -> bf16 (G1) ; MODE 1: bias -> bf16 (G2).
// Ledger: iter t stages tile t+1 (8 loads/thread) into buf[(t+1)&1];
//   vmcnt(8)+barrier => tile t (everyone's loads) landed before compute;
//   trailing barrier => all reads of buf[t&1] done before iter t+1 stages it^... 
//   (iter t+1 stages buf[t&1] only at t+2; overwrite target buf[(t+2)&1]=buf[t&1]
//    is issued after the trailing barrier of iter t+1's predecessor -- safe.)
template <int N_, int K_, int MODE>
__global__ __launch_bounds__(256, 2)
void gemm_bt(const bf16_t* __restrict__ A, const bf16_t* __restrict__ Bt,
             const float* __restrict__ bias, bf16_t* __restrict__ Cout) {
  constexpr int NT = N_ / 128;
  constexpr int T  = K_ / 64;
  __shared__ __align__(16) bf16_t As[2][128 * 64];
  __shared__ __align__(16) bf16_t Bs[2][128 * 64];

  const int per = gridDim.x >> 3;                    // grid % 8 == 0
  const int nb  = (blockIdx.x & 7) * per + (blockIdx.x >> 3);
  const int m0 = (nb / NT) * 128;
  const int n0 = (nb % NT) * 128;

  const int tid = threadIdx.x;
  const int w = tid >> 6, l = tid & 63;
  const int wr = w >> 1, wc = w & 1;
  const int fr = l & 15, fq = l >> 4;

#define STAGE(dst, src, r0, k0)                                               \
  _Pragma("unroll") for (int i = 0; i < 4; ++i) {                             \
    const int G = i * 256 + tid, row = G >> 3, g = G & 7;                     \
    async16((src) + (size_t)((r0) + row) * K_ + (k0) + ((g ^ (row & 7)) << 3),\
            (char*)(dst) + (size_t)(i * 256 + w * 64) * 16);                  \
  }

  STAGE(As[0], A, m0, 0); STAGE(Bs[0], Bt, n0, 0);   // 8 loads/thread in flight

  f32x4 acc[4][4] = {};
#pragma unroll
  for (int t = 0; t < T; ++t) {
    const int cur = t & 1;
    if (t + 1 < T) {
      STAGE(As[cur ^ 1], A, m0, (t + 1) * 64);       // +8 loads (tile t+1)
      STAGE(Bs[cur ^ 1], Bt, n0, (t + 1) * 64);
      asm volatile("s_waitcnt vmcnt(8)" ::: "memory");  // tile t landed (mine)
    } else {
      asm volatile("s_waitcnt vmcnt(0)" ::: "memory");  // last tile: drain
    }
    __builtin_amdgcn_s_barrier();                    // tile t landed (everyone's)
#pragma unroll
    for (int kk = 0; kk < 2; ++kk) {
      bf16x8 ax[4], bx[4];
#pragma unroll
      for (int m = 0; m < 4; ++m) {
        const int row = wr * 64 + m * 16 + fr;
        const int slot = (kk * 4 + fq) ^ (row & 7);
        ax[m] = *(const bf16x8*)((const char*)As[cur] + row * 128 + slot * 16);
      }
#pragma unroll
      for (int n = 0; n < 4; ++n) {
        const int row = wc * 64 + n * 16 + fr;
        const int slot = (kk * 4 + fq) ^ (row & 7);
        bx[n] = *(const bf16x8*)((const char*)Bs[cur] + row * 128 + slot * 16);
      }
#pragma unroll
      for (int m = 0; m < 4; ++m)
#pragma unroll
        for (int n = 0; n < 4; ++n)
          acc[m][n] = __builtin_amdgcn_mfma_f32_16x16x32_bf16(ax[m], bx[n], acc[m][n], 0, 0, 0);
    }
    __builtin_amdgcn_s_barrier();                    // reads of buf[cur] complete
  }
#undef STAGE

  const int orow0 = m0 + wr * 64 + fq * 4;
  const int ocol0 = n0 + wc * 64 + fr;
#pragma unroll
  for (int n = 0; n < 4; ++n) {
    const int col = ocol0 + n * 16;
    const float bv = bias[col];
#pragma unroll
    for (int m = 0; m < 4; ++m)
#pragma unroll
      for (int j = 0; j < 4; ++j) {
        float v = acc[m][n][j] + bv;
        if (MODE == 0) v = fmaxf(v, 0.f);
        Cout[(size_t)(orow0 + m * 16 + j) * N_ + col] = (bf16_t)v;
      }
  }
}

// ---------------------------------------------------------------- LN: bf16 raw -> fp32 out
__global__ __launch_bounds__(256)
void ln_bf16(const bf16_t* __restrict__ raw, const float* __restrict__ gamma,
             const float* __restrict__ beta, float* __restrict__ out) {
  const int r = blockIdx.x * 4 + (threadIdx.x >> 6);
  const int l = threadIdx.x & 63;
  const bf16_t* rp = raw + (size_t)r * HIDDEN;
  float v[12];
  float s = 0.f, q = 0.f;
#pragma unroll
  for (int c = 0; c < 3; ++c) {
    bf16x4 b4 = *(const bf16x4*)(rp + c * 256 + l * 4);
#pragma unroll
    for (int j = 0; j < 4; ++j) {
      const float f = (float)b4[j];
      v[c * 4 + j] = f; s += f; q += f * f;
    }
  }
#pragma unroll
  for (int off = 1; off < 64; off <<= 1) {
    s += __shfl_xor(s, off, 64);
    q += __shfl_xor(q, off, 64);
  }
  const float mu  = s * (1.0f / HIDDEN);
  const float var = fmaxf(q * (1.0f / HIDDEN) - mu * mu, 0.f);
  const float inv = rsqrtf(var + 1e-5f);
  float* op = out + (size_t)r * HIDDEN;
#pragma unroll
  for (int c = 0; c < 3; ++c) {
    float4 g = ((const float4*)gamma)[c * 64 + l];
    float4 b = ((const float4*)beta)[c * 64 + l];
    float4 o;
    o.x = (v[c * 4 + 0] - mu) * inv * g.x + b.x;
    o.y = (v[c * 4 + 1] - mu) * inv * g.y + b.y;
    o.z = (v[c * 4 + 2] - mu) * inv * g.z + b.z;
    o.w = (v[c * 4 + 3] - mu) * inv * g.w + b.w;
    ((float4*)op)[c * 64 + l] = o;
  }
}

// ---------------------------------------------------------------- launch
extern "C" void kernel_launch(void* const* d_in, const int* in_sizes, int n_in,
                              void* d_out, int out_size, void* d_ws, size_t ws_size,
                              hipStream_t stream) {
  const float* x     = (const float*)d_in[0];
  const float* W1    = (const float*)d_in[1];
  const float* b1    = (const float*)d_in[2];
  const float* W2    = (const float*)d_in[3];
  const float* b2    = (const float*)d_in[4];
  const float* Wo    = (const float*)d_in[5];
  const float* bo    = (const float*)d_in[6];
  const float* gamma = (const float*)d_in[7];
  const float* beta  = (const float*)d_in[8];

  const int M = in_sizes[0] / HIDDEN;   // 32768 tokens

  // ws: xb (bf16 M*768, reused as raw after G1) | h (bf16 M*512) | weights
  char* ws = (char*)d_ws;
  bf16_t* xb   = (bf16_t*)ws;
  bf16_t* raw  = xb;                                     // xb dead after G1
  bf16_t* h    = (bf16_t*)(ws + (size_t)M * HIDDEN * 2);
  bf16_t* W1b  = (bf16_t*)(ws + (size_t)M * HIDDEN * 2 + (size_t)M * INNER * 2);
  bf16_t* W2t  = W1b + INNER * HIDDEN;                   // [512,768]
  bf16_t* Wob  = W2t + INNER * HIDDEN;                   // [768,768]
  bf16_t* Weq  = Wob + HIDDEN * HIDDEN;                  // [768,512]
  float*  beq  = (float*)(Weq + HIDDEN * INNER);

  const int xb_blocks = (M * HIDDEN / 4) / 4096;         // 1536

  prep<<<xb_blocks + 156 + 192, 256, 0, stream>>>(x, W1, W2, Wo, b2, bo,
                                                  xb, W1b, W2t, Wob, beq, xb_blocks);
  // Weq = Wo @ W2 : A=Wob [768,768], Bt=W2t [512,768] -> [768,512]
  gemm_weq<<<(HIDDEN / 128) * (INNER / 128), 256, 0, stream>>>(Wob, W2t, Weq);
  // h = relu(xb @ W1^T + b1)
  gemm_bt<INNER, HIDDEN, 0><<<(M / 128) * (INNER / 128), 256, 0, stream>>>(xb, W1b, b1, h);
  // raw = h @ Weq^T + beq
  gemm_bt<HIDDEN, INNER, 1><<<(M / 128) * (HIDDEN / 128), 256, 0, stream>>>(h, Weq, beq, raw);
  // out = LN(raw)
  ln_bf16<<<M / 4, 256, 0, stream>>>(raw, gamma, beta, (float*)d_out);
}